// Round 4
// baseline (3571.319 us; speedup 1.0000x reference)
//
#include <hip/hip_runtime.h>
#include <math.h>

#define NB 8
#define NP 2048
#define KNBR 20
#define NROWS (NB*NP)      // 16384
#define SLOPEV 0.2f
#define EPSV 1e-5f

// ===========================================================================
// Fused KNN: per block, 64 rows x full 2048 cols of one batch.
// For each 64-col tile: fp64 GEMM (identical fma order as the old gemm64 ->
// bitwise-identical distances), dist epilogue, threshold test + LDS survivor
// bitmask, then one merge thread per row inserts survivors into a register-
// resident sorted top-20 list (strict >, ascending col order == jax.lax.top_k
// tie semantics). No D matrix ever touches HBM.
// grid = (NP/64, NB), 256 threads.
// ===========================================================================
__global__ __launch_bounds__(256) void knn_fused(
    const double* __restrict__ F, int lda, int C,
    const double* __restrict__ xx, int* __restrict__ out)
{
    __shared__ double As[16][66];
    __shared__ double Bs[16][66];
    __shared__ double Tile[64][66];
    __shared__ double thr[64];
    __shared__ unsigned mask[64][2];

    const int tid = threadIdx.x;
    const int tx = tid & 15, ty = tid >> 4;
    const int bb = blockIdx.y;
    const int r0 = blockIdx.x * 64;
    const double* Fb  = F  + (size_t)bb * NP * lda;
    const double* xxb = xx + (size_t)bb * NP;

    double kv[KNBR];
    int    ki[KNBR];
#pragma unroll
    for (int q = 0; q < KNBR; ++q) { kv[q] = -INFINITY; ki[q] = 0; }
    if (tid < 64) { thr[tid] = -INFINITY; mask[tid][0] = 0u; mask[tid][1] = 0u; }
    __syncthreads();

    const int ma = tid >> 2, ka = (tid & 3) * 4;   // stage 64 rows x 16 k

    for (int ct = 0; ct < NP / 64; ++ct) {
        const int c0 = ct * 64;
        double acc[4][4];
#pragma unroll
        for (int i = 0; i < 4; ++i)
#pragma unroll
            for (int j = 0; j < 4; ++j) acc[i][j] = 0.0;

        for (int kc = 0; kc < C; kc += 16) {
            const double* ap = Fb + (size_t)(r0 + ma) * lda + kc + ka;
            const double* bp = Fb + (size_t)(c0 + ma) * lda + kc + ka;
#pragma unroll
            for (int i = 0; i < 4; ++i) {
                const int k2 = kc + ka + i;
                As[ka + i][ma] = (k2 < C) ? ap[i] : 0.0;
                Bs[ka + i][ma] = (k2 < C) ? bp[i] : 0.0;
            }
            __syncthreads();
#pragma unroll
            for (int k = 0; k < 16; ++k) {
                double a[4], b[4];
                *(double2*)&a[0] = *(const double2*)&As[k][ty * 4];
                *(double2*)&a[2] = *(const double2*)&As[k][ty * 4 + 2];
                *(double2*)&b[0] = *(const double2*)&Bs[k][tx * 4];
                *(double2*)&b[2] = *(const double2*)&Bs[k][tx * 4 + 2];
#pragma unroll
                for (int i = 0; i < 4; ++i)
#pragma unroll
                    for (int j = 0; j < 4; ++j) acc[i][j] = fma(a[i], b[j], acc[i][j]);
            }
            __syncthreads();
        }

        // epilogue: dist + candidate test (thr stable since last merge+sync)
#pragma unroll
        for (int i = 0; i < 4; ++i) {
            const int r = ty * 4 + i;
            const double xr = xxb[r0 + r];
            const double tr = thr[r];
#pragma unroll
            for (int j = 0; j < 4; ++j) {
                const int c = tx * 4 + j;
                const double d = (2.0 * acc[i][j] - xr) - xxb[c0 + c];  // ref order
                if (d > tr) {
                    Tile[r][c] = d;
                    atomicOr(&mask[r][c >> 5], 1u << (c & 31));
                }
            }
        }
        __syncthreads();

        // merge: one thread per row
        if (tid < 64) {
            bool changed = false;
#pragma unroll
            for (int w = 0; w < 2; ++w) {
                unsigned m = mask[tid][w];
                mask[tid][w] = 0u;
                while (m) {
                    const int b = __ffs(m) - 1;
                    m &= m - 1u;
                    const double v = Tile[tid][w * 32 + b];
                    if (v > kv[KNBR - 1]) {
                        const int col = c0 + w * 32 + b;
                        int pos = 0;
#pragma unroll
                        for (int q = 0; q < KNBR; ++q) pos += (kv[q] >= v) ? 1 : 0;
#pragma unroll
                        for (int q = KNBR - 1; q >= 0; --q) {
                            if (q > pos)       { kv[q] = kv[q - 1]; ki[q] = ki[q - 1]; }
                            else if (q == pos) { kv[q] = v;         ki[q] = col; }
                        }
                        changed = true;
                    }
                }
            }
            if (changed) thr[tid] = kv[KNBR - 1];
        }
        __syncthreads();
    }

    if (tid < 64) {
        int* op = out + ((size_t)bb * NP + r0 + tid) * KNBR;
        const int jbase = bb * NP;
#pragma unroll
        for (int q = 0; q < KNBR; ++q) op[q] = jbase + ki[q];
    }
}

// ===========================================================================
// fp64 GEMM (PQ): C = A(MxK,lda) * B^T(NxK,ldb). 128x64 tile, 8x4 micro.
// XCD-swizzled block map (bx = lin / gridDim.y) for per-XCD A-slab L2 reuse.
// ===========================================================================
#define DK 16
__global__ __launch_bounds__(256) void gemm64(
    const double* __restrict__ A, int lda,
    const double* __restrict__ Bm, int ldb,
    double* __restrict__ Cm, int ldc, int Kd)
{
    __shared__ double As[DK][130];
    __shared__ double Bs[DK][66];
    const int tid = threadIdx.x;
    const int tx = tid & 15, ty = tid >> 4;
    const int lin = blockIdx.y * gridDim.x + blockIdx.x;
    const int bx = lin / gridDim.y;
    const int by = lin - bx * gridDim.y;
    const int row0 = by * 128, col0 = bx * 64;

    double acc[8][4];
#pragma unroll
    for (int i = 0; i < 8; ++i)
#pragma unroll
        for (int j = 0; j < 4; ++j) acc[i][j] = 0.0;

    const int ma = tid >> 1, ka = (tid & 1) * 8;
    const int mb = tid >> 2, kb = (tid & 3) * 4;

    for (int kc = 0; kc < Kd; kc += DK) {
        const double* ap = A + (size_t)(row0 + ma) * lda + kc + ka;
#pragma unroll
        for (int i = 0; i < 8; ++i) {
            const int k2 = kc + ka + i;
            As[ka + i][ma] = (k2 < Kd) ? ap[i] : 0.0;
        }
        const double* bp = Bm + (size_t)(col0 + mb) * ldb + kc + kb;
#pragma unroll
        for (int i = 0; i < 4; ++i) {
            const int k2 = kc + kb + i;
            Bs[kb + i][mb] = (k2 < Kd) ? bp[i] : 0.0;
        }
        __syncthreads();
#pragma unroll
        for (int k = 0; k < DK; ++k) {
            double a[8], b[4];
            *(double2*)&a[0] = *(const double2*)&As[k][ty * 4];
            *(double2*)&a[2] = *(const double2*)&As[k][ty * 4 + 2];
            *(double2*)&a[4] = *(const double2*)&As[k][64 + ty * 4];
            *(double2*)&a[6] = *(const double2*)&As[k][64 + ty * 4 + 2];
            *(double2*)&b[0] = *(const double2*)&Bs[k][tx * 4];
            *(double2*)&b[2] = *(const double2*)&Bs[k][tx * 4 + 2];
#pragma unroll
            for (int i = 0; i < 8; ++i)
#pragma unroll
                for (int j = 0; j < 4; ++j) acc[i][j] = fma(a[i], b[j], acc[i][j]);
        }
        __syncthreads();
    }

#pragma unroll
    for (int i = 0; i < 8; ++i) {
        const int r = row0 + ty * 4 + (i & 3) + ((i >> 2) << 6);
#pragma unroll
        for (int j = 0; j < 4; ++j) {
            const int c = col0 + tx * 4 + j;
            Cm[(size_t)r * ldc + c] = acc[i][j];
        }
    }
}

// ===========================================================================
// fp32 GEMM (MLP): C = A(MxK,lda) * B^T(NxK,ldb), 128x128 tile, 8x8 micro,
// XCD-swizzled block map. mode 2: relu(acc+bias), mode 3: acc+bias.
// a_ss (optional, 2*Kd): A-column scale/shift on load (folded BN).
// ===========================================================================
#define GBK 16
__global__ __launch_bounds__(256) void gemm_f32(
    const float* __restrict__ A, int lda,
    const float* __restrict__ Bm, int ldb,
    float* __restrict__ Cm, int ldc,
    int M, int Nn, int Kd, int mode,
    const float* __restrict__ bias,
    const float* __restrict__ a_ss)
{
    __shared__ float As[GBK][132];
    __shared__ float Bs[GBK][132];
    const int tid = threadIdx.x;
    const int tx = tid & 15, ty = tid >> 4;
    const int lin = blockIdx.y * gridDim.x + blockIdx.x;
    const int bx = lin / gridDim.y;
    const int by = lin - bx * gridDim.y;
    const int row0 = by * 128, col0 = bx * 128;
    float acc[8][8];
#pragma unroll
    for (int i = 0; i < 8; ++i)
#pragma unroll
        for (int j = 0; j < 8; ++j) acc[i][j] = 0.f;

    const int m  = tid >> 1;
    const int kk = (tid & 1) * 8;

    for (int kc = 0; kc < Kd; kc += GBK) {
        const int gr = row0 + m;
        const int gc = col0 + m;
        const float* ap = A  + (size_t)gr * lda + kc + kk;
        const float* bp = Bm + (size_t)gc * ldb + kc + kk;
        const bool full = (kc + GBK <= Kd) && (col0 + 128 <= Nn);
        if (full) {
#pragma unroll
            for (int i = 0; i < 8; ++i) {
                float v = ap[i];
                if (a_ss) { const int k2 = kc + kk + i; v = fmaf(v, a_ss[k2], a_ss[Kd + k2]); }
                As[kk + i][m] = v;
            }
#pragma unroll
            for (int i = 0; i < 8; ++i) Bs[kk + i][m] = bp[i];
        } else {
#pragma unroll
            for (int i = 0; i < 8; ++i) {
                const int k2 = kc + kk + i;
                float v = 0.f;
                if (k2 < Kd) {
                    v = ap[i];
                    if (a_ss) v = fmaf(v, a_ss[k2], a_ss[Kd + k2]);
                }
                As[kk + i][m] = v;
            }
#pragma unroll
            for (int i = 0; i < 8; ++i) {
                const int k2 = kc + kk + i;
                float v = 0.f;
                if (gc < Nn && k2 < Kd) v = bp[i];
                Bs[kk + i][m] = v;
            }
        }
        __syncthreads();
#pragma unroll
        for (int k = 0; k < GBK; ++k) {
            float4 a0 = *(const float4*)&As[k][ty * 4];
            float4 a1 = *(const float4*)&As[k][64 + ty * 4];
            float4 b0 = *(const float4*)&Bs[k][tx * 4];
            float4 b1 = *(const float4*)&Bs[k][64 + tx * 4];
            float a[8] = {a0.x, a0.y, a0.z, a0.w, a1.x, a1.y, a1.z, a1.w};
            float b[8] = {b0.x, b0.y, b0.z, b0.w, b1.x, b1.y, b1.z, b1.w};
#pragma unroll
            for (int i = 0; i < 8; ++i)
#pragma unroll
                for (int j = 0; j < 8; ++j) acc[i][j] = fmaf(a[i], b[j], acc[i][j]);
        }
        __syncthreads();
    }

    const bool vecstore = ((ldc & 3) == 0);
#pragma unroll
    for (int i = 0; i < 8; ++i) {
        const int row = row0 + ty * 4 + (i & 3) + ((i >> 2) << 6);
        if (row >= M) continue;
#pragma unroll
        for (int h = 0; h < 2; ++h) {
            const int c0 = col0 + tx * 4 + (h << 6);
            float v[4];
#pragma unroll
            for (int j = 0; j < 4; ++j) {
                float t = acc[i][h * 4 + j];
                const int col = c0 + j;
                if (col < Nn) {
                    if (mode == 2)      t = fmaxf(t + bias[col], 0.f);
                    else if (mode == 3) t = t + bias[col];
                }
                v[j] = t;
            }
            if (vecstore && (c0 + 3 < Nn)) {
                *(float4*)&Cm[(size_t)row * ldc + c0] = make_float4(v[0], v[1], v[2], v[3]);
            } else {
#pragma unroll
                for (int j = 0; j < 4; ++j)
                    if (c0 + j < Nn) Cm[(size_t)row * ldc + c0 + j] = v[j];
            }
        }
    }
}

// ---------------------------------------------------------------------------
__global__ void f2d_kernel(const float* __restrict__ in, double* __restrict__ out, long n)
{
    long t = (long)blockIdx.x * 256 + threadIdx.x;
    if (t < n) out[t] = (double)in[t];
}
__global__ void d2f_kernel(const double* __restrict__ in, float* __restrict__ out, long n)
{
    long t = (long)blockIdx.x * 256 + threadIdx.x;
    if (t < n) out[t] = (float)in[t];
}

__global__ void xx_kernel_d(const double* __restrict__ F, int lda, int C,
                            double* __restrict__ xx)
{
    int r = blockIdx.x * 256 + threadIdx.x;
    if (r >= NROWS) return;
    const double* p = F + (long)r * lda;
    double s = 0.0;
    for (int c = 0; c < C; ++c) { double v = p[c]; s = fma(v, v, s); }
    xx[r] = s;
}

__global__ void wmod_kernel_d(const float* __restrict__ w, double* __restrict__ wm,
                              int O, int C)
{
    int t = blockIdx.x * 256 + threadIdx.x;
    if (t >= O * C) return;
    int o = t / C, c = t - o * C;
    double a = (double)w[o * 2 * C + c];
    double b = (double)w[o * 2 * C + C + c];
    wm[o * C + c] = a;
    wm[(O + o) * C + c] = b - a;
}

__global__ void transpose_kernel(const float* __restrict__ in, float* __restrict__ out,
                                 int R, int C)
{
    long t = (long)blockIdx.x * 256 + threadIdx.x;
    if (t >= (long)R * C) return;
    int r = (int)(t / C), c = (int)(t - (long)r * C);
    out[(long)c * R + r] = in[t];
}

// ---------------------------------------------------------------------------
// EdgeConv BN stats (fp64): per-channel sum/sumsq of h = P[idx] + Q
// ---------------------------------------------------------------------------
__global__ __launch_bounds__(256) void edge_stats_d(const double* __restrict__ PQ,
                                                    const int* __restrict__ idx,
                                                    int O, int shiftO,
                                                    double* __restrict__ sums)
{
    const int tid = threadIdx.x;
    const int o = tid & (O - 1);
    const int q = tid >> shiftO;
    const int nsub = 256 >> shiftO;
    const int r0 = blockIdx.x * 16;
    const int ld = 2 * O;
    double s = 0.0, ss = 0.0;
    for (int r = r0 + q; r < r0 + 16; r += nsub) {
        double qv = PQ[(long)r * ld + O + o];
        const int* ip = idx + r * KNBR;
        for (int k = 0; k < KNBR; ++k) {
            int j = ip[k];
            double v = PQ[(long)j * ld + o] + qv;
            s += v; ss = fma(v, v, ss);
        }
    }
    __shared__ double red[256];
    red[tid] = s; __syncthreads();
    if (q == 0) for (int qq = 1; qq < nsub; ++qq) s += red[o + (qq << shiftO)];
    __syncthreads();
    red[tid] = ss; __syncthreads();
    if (q == 0) {
        for (int qq = 1; qq < nsub; ++qq) ss += red[o + (qq << shiftO)];
        atomicAdd(&sums[o], s);
        atomicAdd(&sums[O + o], ss);
    }
}

__global__ void bn_finalize_d(const double* __restrict__ sums,
                              const float* __restrict__ g, const float* __restrict__ b,
                              double* __restrict__ ss, int O, double invCnt)
{
    int o = blockIdx.x * 256 + threadIdx.x;
    if (o >= O) return;
    double mu  = sums[o] * invCnt;
    double var = sums[O + o] * invCnt - mu * mu;
    double is  = 1.0 / sqrt(var + 1e-5);
    double sc  = (double)g[o] * is;
    ss[o] = sc;
    ss[O + o] = (double)b[o] - mu * sc;
}

__global__ __launch_bounds__(256) void edge_pool_d(const double* __restrict__ PQ,
                                                   const int* __restrict__ idx,
                                                   const double* __restrict__ ssb,
                                                   double* __restrict__ outF,
                                                   int O, int shiftO, int ldo)
{
    const int tid = threadIdx.x;
    const int o = tid & (O - 1);
    const int r = blockIdx.x * (256 >> shiftO) + (tid >> shiftO);
    const int ld = 2 * O;
    const double sc = ssb[o], sh = ssb[O + o];
    const double qv = PQ[(long)r * ld + O + o];
    const int* ip = idx + r * KNBR;
    double m = -INFINITY;
    for (int k = 0; k < KNBR; ++k) {
        int j = ip[k];
        double v = fma(PQ[(long)j * ld + o] + qv, sc, sh);
        v = v > 0.0 ? v : 0.2 * v;
        m = fmax(m, v);
    }
    outF[(long)r * ldo + o] = m;
}

// ---------------------------------------------------------------------------
__global__ void col_stats(const float* __restrict__ Y, int ncol,
                          float* __restrict__ sums)
{
    int c  = blockIdx.x * 128 + threadIdx.x;
    int r0 = blockIdx.y * 256;
    float s = 0.f, ss = 0.f;
    for (int r = r0; r < r0 + 256; ++r) {
        float v = Y[(long)r * ncol + c];
        s += v; ss = fmaf(v, v, ss);
    }
    atomicAdd(&sums[c], s);
    atomicAdd(&sums[ncol + c], ss);
}

__global__ void bn_finalize_f(const float* __restrict__ sums,
                              const float* __restrict__ g, const float* __restrict__ b,
                              float* __restrict__ ss, int O, float invCnt)
{
    int o = blockIdx.x * 256 + threadIdx.x;
    if (o >= O) return;
    float mu  = sums[o] * invCnt;
    float var = sums[O + o] * invCnt - mu * mu;
    float is  = rsqrtf(var + EPSV);
    float sc  = g[o] * is;
    ss[o] = sc;
    ss[O + o] = b[o] - mu * sc;
}

__global__ __launch_bounds__(256) void log_softmax_kernel(float* __restrict__ Y)
{
    const int lane = threadIdx.x & 63;
    const int row  = blockIdx.x * 4 + (threadIdx.x >> 6);
    float v = -INFINITY;
    if (lane < 50) v = Y[(long)row * 50 + lane];
    float mx = v;
#pragma unroll
    for (int off = 32; off >= 1; off >>= 1) mx = fmaxf(mx, __shfl_xor(mx, off, 64));
    float e = (lane < 50) ? expf(v - mx) : 0.f;
    float s = e;
#pragma unroll
    for (int off = 32; off >= 1; off >>= 1) s += __shfl_xor(s, off, 64);
    float l = logf(s) + mx;
    if (lane < 50) Y[(long)row * 50 + lane] = v - l;
}

// ===========================================================================
extern "C" void kernel_launch(void* const* d_in, const int* in_sizes, int n_in,
                              void* d_out, int out_size, void* d_ws, size_t ws_size,
                              hipStream_t stream)
{
    const float* x   = (const float*)d_in[0];
    const float* w[4]  = {(const float*)d_in[4], (const float*)d_in[7],
                          (const float*)d_in[10], (const float*)d_in[13]};
    const float* g[4]  = {(const float*)d_in[5], (const float*)d_in[8],
                          (const float*)d_in[11], (const float*)d_in[14]};
    const float* bb[4] = {(const float*)d_in[6], (const float*)d_in[9],
                          (const float*)d_in[12], (const float*)d_in[15]};
    const float* lw1 = (const float*)d_in[16]; const float* lb1 = (const float*)d_in[17];
    const float* lg1 = (const float*)d_in[18]; const float* lbb1 = (const float*)d_in[19];
    const float* mw1 = (const float*)d_in[20]; const float* mb1 = (const float*)d_in[21];
    const float* mg1 = (const float*)d_in[22]; const float* mbb1 = (const float*)d_in[23];
    const float* mw2 = (const float*)d_in[24]; const float* mb2 = (const float*)d_in[25];
    const float* mg2 = (const float*)d_in[26]; const float* mbb2 = (const float*)d_in[27];
    const float* hw  = (const float*)d_in[28]; const float* hb  = (const float*)d_in[29];
    float* out = (float*)d_out;

    // ---- workspace layout (bytes) ----
    char* base = (char*)d_ws;
    double* catD = (double*)base;                       // 64 MB
    char*  un    = base + 67108864;                     // 64 MB union region
    double* PQ   = (double*)un;                         // up to 64 MB
    float* cat32 = (float*)un;                          // 32 MB (MLP phase)
    float* Y2    = (float*)(un + 33554432);             // 16 MB
    float* Y3    = (float*)(un + 50331648);             // 8 MB
    float* lw1T  = (float*)(un + 58720256);             // 2 MB
    float* mw1T  = (float*)(un + 60817408);             // 1 MB
    float* mw2T  = (float*)(un + 61865984);             // 128 KB
    float* hwT   = (float*)(un + 61997056);             // 25.6 KB
    float* Y1    = (float*)base;                        // aliases catD (dead after d2f)
    char* tail = base + 2u * 67108864u;
    int*    idxb  = (int*)tail;                         // 1.25 MB
    double* xD    = (double*)(tail + 1310720);          // 384 KB
    double* xxD   = (double*)(tail + 1703936);          // 128 KB
    double* wmodD = (double*)(tail + 1835008);          // 512 KB
    double* sumsD = (double*)(tail + 2359296);          // 8 KB
    double* ssbD  = (double*)(tail + 2367488);          // 8 KB
    float*  sumsF = (float*)(tail + 2375680);           // 8 KB
    float*  ssbF  = (float*)(tail + 2383872);           // 8 KB

    // ---- x -> fp64 ----
    f2d_kernel<<<(NROWS * 3 + 255) / 256, 256, 0, stream>>>(x, xD, (long)NROWS * 3);

    // ---- 4 EdgeConv layers (all fp64) ----
    const double* Fin[4] = {xD, catD + 0, catD + 64, catD + 128};
    const int   ldaL[4] = {3, 512, 512, 512};
    const int   CL[4]   = {3, 64, 64, 128};
    const int   OL[4]   = {64, 64, 128, 256};
    const int   coff[4] = {0, 64, 128, 256};

    for (int l = 0; l < 4; ++l) {
        const double* F = Fin[l];
        const int lda = ldaL[l], C = CL[l], O = OL[l];
        const int shiftO = (O == 64) ? 6 : (O == 128) ? 7 : 8;

        wmod_kernel_d<<<(O * C + 255) / 256, 256, 0, stream>>>(w[l], wmodD, O, C);
        xx_kernel_d<<<NROWS / 256, 256, 0, stream>>>(F, lda, C, xxD);

        // fused dist + top-20 (no D materialization)
        knn_fused<<<dim3(NP / 64, NB), 256, 0, stream>>>(F, lda, C, xxD, idxb);

        gemm64<<<dim3((2 * O) / 64, NROWS / 128), 256, 0, stream>>>(
            F, lda, wmodD, C, PQ, 2 * O, C);

        hipMemsetAsync(sumsD, 0, 2 * O * sizeof(double), stream);
        edge_stats_d<<<NROWS / 16, 256, 0, stream>>>(PQ, idxb, O, shiftO, sumsD);
        bn_finalize_d<<<(O + 255) / 256, 256, 0, stream>>>(sumsD, g[l], bb[l], ssbD, O,
                                                           1.0 / ((double)NROWS * KNBR));
        edge_pool_d<<<(NROWS * O) / 256, 256, 0, stream>>>(PQ, idxb, ssbD,
                                                           catD + coff[l], O, shiftO, 512);
    }

    // ---- cat fp64 -> fp32 (catD region becomes free -> Y1) ----
    d2f_kernel<<<((long)NROWS * 512 + 255) / 256, 256, 0, stream>>>(catD, cat32, (long)NROWS * 512);

    // ---- weight transposes ----
    transpose_kernel<<<(512 * 1024 + 255) / 256, 256, 0, stream>>>(lw1, lw1T, 512, 1024);
    transpose_kernel<<<(1024 * 256 + 255) / 256, 256, 0, stream>>>(mw1, mw1T, 1024, 256);
    transpose_kernel<<<(256 * 128 + 255) / 256, 256, 0, stream>>>(mw2, mw2T, 256, 128);
    transpose_kernel<<<(128 * 50 + 255) / 256, 256, 0, stream>>>(hw, hwT, 128, 50);

    // ---- MLP (fp32) ----
    {
        dim3 gg(1024 / 128, NROWS / 128);
        gemm_f32<<<gg, 256, 0, stream>>>(cat32, 512, lw1T, 512, Y1, 1024,
                                         NROWS, 1024, 512, 2, lb1, nullptr);
        hipMemsetAsync(sumsF, 0, 2 * 1024 * sizeof(float), stream);
        col_stats<<<dim3(1024 / 128, 64), 128, 0, stream>>>(Y1, 1024, sumsF);
        bn_finalize_f<<<4, 256, 0, stream>>>(sumsF, lg1, lbb1, ssbF, 1024, 1.f / NROWS);
    }
    {
        dim3 gg(256 / 128, NROWS / 128);
        gemm_f32<<<gg, 256, 0, stream>>>(Y1, 1024, mw1T, 1024, Y2, 256,
                                         NROWS, 256, 1024, 2, mb1, ssbF);
        hipMemsetAsync(sumsF, 0, 2 * 256 * sizeof(float), stream);
        col_stats<<<dim3(256 / 128, 64), 128, 0, stream>>>(Y2, 256, sumsF);
        bn_finalize_f<<<1, 256, 0, stream>>>(sumsF, mg1, mbb1, ssbF, 256, 1.f / NROWS);
    }
    {
        dim3 gg(1, NROWS / 128);
        gemm_f32<<<gg, 256, 0, stream>>>(Y2, 256, mw2T, 256, Y3, 128,
                                         NROWS, 128, 256, 2, mb2, ssbF);
        hipMemsetAsync(sumsF, 0, 2 * 128 * sizeof(float), stream);
        col_stats<<<dim3(1, 64), 128, 0, stream>>>(Y3, 128, sumsF);
        bn_finalize_f<<<1, 256, 0, stream>>>(sumsF, mg2, mbb2, ssbF, 128, 1.f / NROWS);
    }
    {
        dim3 gg(1, NROWS / 128);
        gemm_f32<<<gg, 256, 0, stream>>>(Y3, 128, hwT, 128, out, 50,
                                         NROWS, 50, 128, 3, hb, ssbF);
        log_softmax_kernel<<<NROWS / 4, 256, 0, stream>>>(out);
    }
}

// Round 5
// 2811.078 us; speedup vs baseline: 1.2704x; 1.2704x over previous
//
#include <hip/hip_runtime.h>
#include <math.h>

#define NB 8
#define NP 2048
#define KNBR 20
#define NROWS (NB*NP)      // 16384
#define SLOPEV 0.2f
#define EPSV 1e-5f

// ===========================================================================
// fp64 dist GEMM: per batch, lower block-band of the symmetric 2048x2048
// matrix (272 tiles of 128x64), mirror-written with row-consistent rounding
// (bitwise-identical duplicates). grid=(272, 2 batches).
// ===========================================================================
#define DK 16
__global__ __launch_bounds__(256) void gemm64_dist(
    const double* __restrict__ A, int lda, int Kd,
    const double* __restrict__ xx, double* __restrict__ Cm, int batch0)
{
    __shared__ double As[DK][130];
    __shared__ double Bs[DK][66];
    const int tid = threadIdx.x;
    const int tx = tid & 15, ty = tid >> 4;
    const int bb = blockIdx.y;
    const int x  = blockIdx.x;
    int bi = (int)((sqrtf(4.0f * x + 1.0f) - 1.0f) * 0.5f);
    while (bi * (bi + 1) > x) --bi;
    while ((bi + 1) * (bi + 2) <= x) ++bi;
    const int bj = x - bi * (bi + 1);
    const int row0 = bi * 128, col0 = bj * 64;
    const double* Ab  = A + (size_t)(batch0 + bb) * NP * lda;
    double*       Cb  = Cm + (size_t)bb * NP * NP;
    const double* xxb = xx + (size_t)(batch0 + bb) * NP;

    double acc[8][4];
#pragma unroll
    for (int i = 0; i < 8; ++i)
#pragma unroll
        for (int j = 0; j < 4; ++j) acc[i][j] = 0.0;

    const int ma = tid >> 1, ka = (tid & 1) * 8;
    const int mb = tid >> 2, kb = (tid & 3) * 4;

    for (int kc = 0; kc < Kd; kc += DK) {
        const double* ap = Ab + (size_t)(row0 + ma) * lda + kc + ka;
#pragma unroll
        for (int i = 0; i < 8; ++i) {
            const int k2 = kc + ka + i;
            As[ka + i][ma] = (k2 < Kd) ? ap[i] : 0.0;
        }
        const double* bp = Ab + (size_t)(col0 + mb) * lda + kc + kb;
#pragma unroll
        for (int i = 0; i < 4; ++i) {
            const int k2 = kc + kb + i;
            Bs[kb + i][mb] = (k2 < Kd) ? bp[i] : 0.0;
        }
        __syncthreads();
#pragma unroll
        for (int k = 0; k < DK; ++k) {
            double a[8], b[4];
            *(double2*)&a[0] = *(const double2*)&As[k][ty * 4];
            *(double2*)&a[2] = *(const double2*)&As[k][ty * 4 + 2];
            *(double2*)&a[4] = *(const double2*)&As[k][64 + ty * 4];
            *(double2*)&a[6] = *(const double2*)&As[k][64 + ty * 4 + 2];
            *(double2*)&b[0] = *(const double2*)&Bs[k][tx * 4];
            *(double2*)&b[2] = *(const double2*)&Bs[k][tx * 4 + 2];
#pragma unroll
            for (int i = 0; i < 8; ++i)
#pragma unroll
                for (int j = 0; j < 4; ++j) acc[i][j] = fma(a[i], b[j], acc[i][j]);
        }
        __syncthreads();
    }

#pragma unroll
    for (int i = 0; i < 8; ++i) {
        const int r = row0 + ty * 4 + (i & 3) + ((i >> 2) << 6);
        const double xr = xxb[r];
#pragma unroll
        for (int j = 0; j < 4; ++j) {
            const int c = col0 + tx * 4 + j;
            const double a2 = 2.0 * acc[i][j];
            const double xc = xxb[c];
            Cb[(size_t)r * NP + c] = (a2 - xr) - xc;   // reference order
            Cb[(size_t)c * NP + r] = (a2 - xc) - xr;   // mirror, row-consistent
        }
    }
}

// ===========================================================================
// fp64 GEMM (PQ): C = A(MxK,lda) * B^T(NxK,ldb). 128x64 tile, 8x4 micro.
// XCD-swizzled block map.
// ===========================================================================
__global__ __launch_bounds__(256) void gemm64(
    const double* __restrict__ A, int lda,
    const double* __restrict__ Bm, int ldb,
    double* __restrict__ Cm, int ldc, int Kd)
{
    __shared__ double As[DK][130];
    __shared__ double Bs[DK][66];
    const int tid = threadIdx.x;
    const int tx = tid & 15, ty = tid >> 4;
    const int lin = blockIdx.y * gridDim.x + blockIdx.x;
    const int bx = lin / gridDim.y;
    const int by = lin - bx * gridDim.y;
    const int row0 = by * 128, col0 = bx * 64;

    double acc[8][4];
#pragma unroll
    for (int i = 0; i < 8; ++i)
#pragma unroll
        for (int j = 0; j < 4; ++j) acc[i][j] = 0.0;

    const int ma = tid >> 1, ka = (tid & 1) * 8;
    const int mb = tid >> 2, kb = (tid & 3) * 4;

    for (int kc = 0; kc < Kd; kc += DK) {
        const double* ap = A + (size_t)(row0 + ma) * lda + kc + ka;
#pragma unroll
        for (int i = 0; i < 8; ++i) {
            const int k2 = kc + ka + i;
            As[ka + i][ma] = (k2 < Kd) ? ap[i] : 0.0;
        }
        const double* bp = Bm + (size_t)(col0 + mb) * ldb + kc + kb;
#pragma unroll
        for (int i = 0; i < 4; ++i) {
            const int k2 = kc + kb + i;
            Bs[kb + i][mb] = (k2 < Kd) ? bp[i] : 0.0;
        }
        __syncthreads();
#pragma unroll
        for (int k = 0; k < DK; ++k) {
            double a[8], b[4];
            *(double2*)&a[0] = *(const double2*)&As[k][ty * 4];
            *(double2*)&a[2] = *(const double2*)&As[k][ty * 4 + 2];
            *(double2*)&a[4] = *(const double2*)&As[k][64 + ty * 4];
            *(double2*)&a[6] = *(const double2*)&As[k][64 + ty * 4 + 2];
            *(double2*)&b[0] = *(const double2*)&Bs[k][tx * 4];
            *(double2*)&b[2] = *(const double2*)&Bs[k][tx * 4 + 2];
#pragma unroll
            for (int i = 0; i < 8; ++i)
#pragma unroll
                for (int j = 0; j < 4; ++j) acc[i][j] = fma(a[i], b[j], acc[i][j]);
        }
        __syncthreads();
    }

#pragma unroll
    for (int i = 0; i < 8; ++i) {
        const int r = row0 + ty * 4 + (i & 3) + ((i >> 2) << 6);
#pragma unroll
        for (int j = 0; j < 4; ++j) {
            const int c = col0 + tx * 4 + j;
            Cm[(size_t)r * ldc + c] = acc[i][j];
        }
    }
}

// ===========================================================================
// fp32 GEMM (MLP): 128x128 tile, 8x8 micro, XCD-swizzled.
// mode 2: relu(acc+bias), mode 3: acc+bias. a_ss: folded BN on A-load.
// ===========================================================================
#define GBK 16
__global__ __launch_bounds__(256) void gemm_f32(
    const float* __restrict__ A, int lda,
    const float* __restrict__ Bm, int ldb,
    float* __restrict__ Cm, int ldc,
    int M, int Nn, int Kd, int mode,
    const float* __restrict__ bias,
    const float* __restrict__ a_ss)
{
    __shared__ float As[GBK][132];
    __shared__ float Bs[GBK][132];
    const int tid = threadIdx.x;
    const int tx = tid & 15, ty = tid >> 4;
    const int lin = blockIdx.y * gridDim.x + blockIdx.x;
    const int bx = lin / gridDim.y;
    const int by = lin - bx * gridDim.y;
    const int row0 = by * 128, col0 = bx * 128;
    float acc[8][8];
#pragma unroll
    for (int i = 0; i < 8; ++i)
#pragma unroll
        for (int j = 0; j < 8; ++j) acc[i][j] = 0.f;

    const int m  = tid >> 1;
    const int kk = (tid & 1) * 8;

    for (int kc = 0; kc < Kd; kc += GBK) {
        const int gr = row0 + m;
        const int gc = col0 + m;
        const float* ap = A  + (size_t)gr * lda + kc + kk;
        const float* bp = Bm + (size_t)gc * ldb + kc + kk;
        const bool full = (kc + GBK <= Kd) && (col0 + 128 <= Nn);
        if (full) {
#pragma unroll
            for (int i = 0; i < 8; ++i) {
                float v = ap[i];
                if (a_ss) { const int k2 = kc + kk + i; v = fmaf(v, a_ss[k2], a_ss[Kd + k2]); }
                As[kk + i][m] = v;
            }
#pragma unroll
            for (int i = 0; i < 8; ++i) Bs[kk + i][m] = bp[i];
        } else {
#pragma unroll
            for (int i = 0; i < 8; ++i) {
                const int k2 = kc + kk + i;
                float v = 0.f;
                if (k2 < Kd) {
                    v = ap[i];
                    if (a_ss) v = fmaf(v, a_ss[k2], a_ss[Kd + k2]);
                }
                As[kk + i][m] = v;
            }
#pragma unroll
            for (int i = 0; i < 8; ++i) {
                const int k2 = kc + kk + i;
                float v = 0.f;
                if (gc < Nn && k2 < Kd) v = bp[i];
                Bs[kk + i][m] = v;
            }
        }
        __syncthreads();
#pragma unroll
        for (int k = 0; k < GBK; ++k) {
            float4 a0 = *(const float4*)&As[k][ty * 4];
            float4 a1 = *(const float4*)&As[k][64 + ty * 4];
            float4 b0 = *(const float4*)&Bs[k][tx * 4];
            float4 b1 = *(const float4*)&Bs[k][64 + tx * 4];
            float a[8] = {a0.x, a0.y, a0.z, a0.w, a1.x, a1.y, a1.z, a1.w};
            float b[8] = {b0.x, b0.y, b0.z, b0.w, b1.x, b1.y, b1.z, b1.w};
#pragma unroll
            for (int i = 0; i < 8; ++i)
#pragma unroll
                for (int j = 0; j < 8; ++j) acc[i][j] = fmaf(a[i], b[j], acc[i][j]);
        }
        __syncthreads();
    }

    const bool vecstore = ((ldc & 3) == 0);
#pragma unroll
    for (int i = 0; i < 8; ++i) {
        const int row = row0 + ty * 4 + (i & 3) + ((i >> 2) << 6);
        if (row >= M) continue;
#pragma unroll
        for (int h = 0; h < 2; ++h) {
            const int c0 = col0 + tx * 4 + (h << 6);
            float v[4];
#pragma unroll
            for (int j = 0; j < 4; ++j) {
                float t = acc[i][h * 4 + j];
                const int col = c0 + j;
                if (col < Nn) {
                    if (mode == 2)      t = fmaxf(t + bias[col], 0.f);
                    else if (mode == 3) t = t + bias[col];
                }
                v[j] = t;
            }
            if (vecstore && (c0 + 3 < Nn)) {
                *(float4*)&Cm[(size_t)row * ldc + c0] = make_float4(v[0], v[1], v[2], v[3]);
            } else {
#pragma unroll
                for (int j = 0; j < 4; ++j)
                    if (c0 + j < Nn) Cm[(size_t)row * ldc + c0 + j] = v[j];
            }
        }
    }
}

// ---------------------------------------------------------------------------
__global__ void f2d_kernel(const float* __restrict__ in, double* __restrict__ out, long n)
{
    long t = (long)blockIdx.x * 256 + threadIdx.x;
    if (t < n) out[t] = (double)in[t];
}
__global__ void d2f_kernel(const double* __restrict__ in, float* __restrict__ out, long n)
{
    long t = (long)blockIdx.x * 256 + threadIdx.x;
    if (t < n) out[t] = (float)in[t];
}

__global__ void xx_kernel_d(const double* __restrict__ F, int lda, int C,
                            double* __restrict__ xx)
{
    int r = blockIdx.x * 256 + threadIdx.x;
    if (r >= NROWS) return;
    const double* p = F + (long)r * lda;
    double s = 0.0;
    for (int c = 0; c < C; ++c) { double v = p[c]; s = fma(v, v, s); }
    xx[r] = s;
}

__global__ void wmod_kernel_d(const float* __restrict__ w, double* __restrict__ wm,
                              int O, int C)
{
    int t = blockIdx.x * 256 + threadIdx.x;
    if (t >= O * C) return;
    int o = t / C, c = t - o * C;
    double a = (double)w[o * 2 * C + c];
    double b = (double)w[o * 2 * C + C + c];
    wm[o * C + c] = a;
    wm[(O + o) * C + c] = b - a;
}

__global__ void transpose_kernel(const float* __restrict__ in, float* __restrict__ out,
                                 int R, int C)
{
    long t = (long)blockIdx.x * 256 + threadIdx.x;
    if (t >= (long)R * C) return;
    int r = (int)(t / C), c = (int)(t - (long)r * C);
    out[(long)c * R + r] = in[t];
}

// ---------------------------------------------------------------------------
// top-20 per 2048-wide fp64 row. 1 wave/row, 4 rows/block, 2 batches (grid.y).
// Incremental per-lane best; tie-break = lower col (jax.lax.top_k semantics).
// ---------------------------------------------------------------------------
__global__ __launch_bounds__(256) void topk2(const double* __restrict__ D,
                                             int* __restrict__ out, int batch0)
{
    const int lane = threadIdx.x & 63;
    const int bb   = blockIdx.y;
    const int row  = blockIdx.x * 4 + (threadIdx.x >> 6);
    const double* rp = D + (size_t)bb * NP * NP + (size_t)row * NP;
    double v[32];
#pragma unroll
    for (int j = 0; j < 16; ++j) {
        double2 p = *(const double2*)&rp[j * 128 + lane * 2];
        v[2 * j] = p.x; v[2 * j + 1] = p.y;
    }
    double lbest = v[0];
    int    lidx  = lane * 2;
#pragma unroll
    for (int q = 1; q < 32; ++q) {
        const int col = ((q >> 1) << 7) + lane * 2 + (q & 1);
        if (v[q] > lbest) { lbest = v[q]; lidx = col; }
    }

    int* op = out + ((size_t)(batch0 + bb) * NP + row) * KNBR;
    const int jbase = (batch0 + bb) * NP;

    for (int it = 0; it < KNBR; ++it) {
        double best = lbest; int bidx = lidx;
#pragma unroll
        for (int off = 32; off >= 1; off >>= 1) {
            double ov = __shfl_xor(best, off, 64);
            int    oi = __shfl_xor(bidx, off, 64);
            if (ov > best || (ov == best && oi < bidx)) { best = ov; bidx = oi; }
        }
        if (lane == 0) op[it] = jbase + bidx;
        if (lane == ((bidx >> 1) & 63)) {
            const int q = (((bidx >> 7) << 1) | (bidx & 1));
#pragma unroll
            for (int qq = 0; qq < 32; ++qq) if (qq == q) v[qq] = -INFINITY;
            lbest = v[0]; lidx = lane * 2;
#pragma unroll
            for (int qq = 1; qq < 32; ++qq) {
                const int col = ((qq >> 1) << 7) + lane * 2 + (qq & 1);
                if (v[qq] > lbest) { lbest = v[qq]; lidx = col; }
            }
        }
    }
}

// ---------------------------------------------------------------------------
// SINGLE gather pass: per (r,o) computes h_k = P[idx[r,k],o] + Q[r,o] for all
// k, accumulating per-channel sum/sumsq (-> sums) AND writing the pre-BN max
// into catOut[r*ldo+o]. (max commutes with the monotone BN+leaky applied
// later since sc>0; sc<0 fallback handled in bn_apply.)
// ---------------------------------------------------------------------------
__global__ __launch_bounds__(256) void edge_gather(const double* __restrict__ PQ,
                                                   const int* __restrict__ idx,
                                                   int O, int shiftO,
                                                   double* __restrict__ sums,
                                                   double* __restrict__ catOut, int ldo)
{
    const int tid = threadIdx.x;
    const int o = tid & (O - 1);
    const int q = tid >> shiftO;
    const int nsub = 256 >> shiftO;
    const int r0 = blockIdx.x * 16;
    const int ld = 2 * O;
    double s = 0.0, ss = 0.0;
    for (int r = r0 + q; r < r0 + 16; r += nsub) {
        const double qv = PQ[(size_t)r * ld + O + o];
        const int* ip = idx + r * KNBR;
        double m = -INFINITY;
        for (int k = 0; k < KNBR; ++k) {
            const int j = ip[k];
            const double v = PQ[(size_t)j * ld + o] + qv;
            s += v; ss = fma(v, v, ss);
            m = fmax(m, v);
        }
        catOut[(size_t)r * ldo + o] = m;
    }
    __shared__ double red[256];
    red[tid] = s; __syncthreads();
    if (q == 0) for (int qq = 1; qq < nsub; ++qq) s += red[o + (qq << shiftO)];
    __syncthreads();
    red[tid] = ss; __syncthreads();
    if (q == 0) {
        for (int qq = 1; qq < nsub; ++qq) ss += red[o + (qq << shiftO)];
        atomicAdd(&sums[o], s);
        atomicAdd(&sums[O + o], ss);
    }
}

__global__ void bn_finalize_d(const double* __restrict__ sums,
                              const float* __restrict__ g, const float* __restrict__ b,
                              double* __restrict__ ss, int O, double invCnt)
{
    int o = blockIdx.x * 256 + threadIdx.x;
    if (o >= O) return;
    double mu  = sums[o] * invCnt;
    double var = sums[O + o] * invCnt - mu * mu;
    double is  = 1.0 / sqrt(var + 1e-5);
    double sc  = (double)g[o] * is;
    ss[o] = sc;
    ss[O + o] = (double)b[o] - mu * sc;
}

// ---------------------------------------------------------------------------
// elementwise BN+leaky applied in place to the pre-BN max stored in catOut.
// sc<0 fallback re-gathers the min (never taken for g>0; kept for safety).
// ---------------------------------------------------------------------------
__global__ __launch_bounds__(256) void bn_apply(double* __restrict__ catOut, int ldo,
                                                const double* __restrict__ ssb,
                                                int O, int shiftO,
                                                const double* __restrict__ PQ,
                                                const int* __restrict__ idx)
{
    const int t = blockIdx.x * 256 + threadIdx.x;
    const int o = t & (O - 1);
    const int r = t >> shiftO;
    const double sc = ssb[o], sh = ssb[O + o];
    double v = catOut[(size_t)r * ldo + o];
    if (sc < 0.0) {                       // rare path: min instead of max
        const int ld = 2 * O;
        const double qv = PQ[(size_t)r * ld + O + o];
        const int* ip = idx + r * KNBR;
        double m = INFINITY;
        for (int k = 0; k < KNBR; ++k)
            m = fmin(m, PQ[(size_t)ip[k] * ld + o] + qv);
        v = m;
    }
    double u = fma(v, sc, sh);
    u = u > 0.0 ? u : 0.2 * u;
    catOut[(size_t)r * ldo + o] = u;
}

// ---------------------------------------------------------------------------
__global__ void col_stats(const float* __restrict__ Y, int ncol,
                          float* __restrict__ sums)
{
    int c  = blockIdx.x * 128 + threadIdx.x;
    int r0 = blockIdx.y * 256;
    float s = 0.f, ss = 0.f;
    for (int r = r0; r < r0 + 256; ++r) {
        float v = Y[(long)r * ncol + c];
        s += v; ss = fmaf(v, v, ss);
    }
    atomicAdd(&sums[c], s);
    atomicAdd(&sums[ncol + c], ss);
}

__global__ void bn_finalize_f(const float* __restrict__ sums,
                              const float* __restrict__ g, const float* __restrict__ b,
                              float* __restrict__ ss, int O, float invCnt)
{
    int o = blockIdx.x * 256 + threadIdx.x;
    if (o >= O) return;
    float mu  = sums[o] * invCnt;
    float var = sums[O + o] * invCnt - mu * mu;
    float is  = rsqrtf(var + EPSV);
    float sc  = g[o] * is;
    ss[o] = sc;
    ss[O + o] = b[o] - mu * sc;
}

__global__ __launch_bounds__(256) void log_softmax_kernel(float* __restrict__ Y)
{
    const int lane = threadIdx.x & 63;
    const int row  = blockIdx.x * 4 + (threadIdx.x >> 6);
    float v = -INFINITY;
    if (lane < 50) v = Y[(long)row * 50 + lane];
    float mx = v;
#pragma unroll
    for (int off = 32; off >= 1; off >>= 1) mx = fmaxf(mx, __shfl_xor(mx, off, 64));
    float e = (lane < 50) ? expf(v - mx) : 0.f;
    float s = e;
#pragma unroll
    for (int off = 32; off >= 1; off >>= 1) s += __shfl_xor(s, off, 64);
    float l = logf(s) + mx;
    if (lane < 50) Y[(long)row * 50 + lane] = v - l;
}

// ===========================================================================
extern "C" void kernel_launch(void* const* d_in, const int* in_sizes, int n_in,
                              void* d_out, int out_size, void* d_ws, size_t ws_size,
                              hipStream_t stream)
{
    const float* x   = (const float*)d_in[0];
    const float* w[4]  = {(const float*)d_in[4], (const float*)d_in[7],
                          (const float*)d_in[10], (const float*)d_in[13]};
    const float* g[4]  = {(const float*)d_in[5], (const float*)d_in[8],
                          (const float*)d_in[11], (const float*)d_in[14]};
    const float* bb[4] = {(const float*)d_in[6], (const float*)d_in[9],
                          (const float*)d_in[12], (const float*)d_in[15]};
    const float* lw1 = (const float*)d_in[16]; const float* lb1 = (const float*)d_in[17];
    const float* lg1 = (const float*)d_in[18]; const float* lbb1 = (const float*)d_in[19];
    const float* mw1 = (const float*)d_in[20]; const float* mb1 = (const float*)d_in[21];
    const float* mg1 = (const float*)d_in[22]; const float* mbb1 = (const float*)d_in[23];
    const float* mw2 = (const float*)d_in[24]; const float* mb2 = (const float*)d_in[25];
    const float* mg2 = (const float*)d_in[26]; const float* mbb2 = (const float*)d_in[27];
    const float* hw  = (const float*)d_in[28]; const float* hb  = (const float*)d_in[29];
    float* out = (float*)d_out;

    // ---- workspace layout (bytes) ----
    char* base = (char*)d_ws;
    double* catD = (double*)base;                       // 64 MB
    char*  un    = base + 67108864;                     // 64 MB union region
    double* D    = (double*)un;                         // 2 batches x 32 MB
    double* PQ   = (double*)un;                         // up to 64 MB (after topk)
    float* cat32 = (float*)un;                          // 32 MB (MLP phase)
    float* Y2    = (float*)(un + 33554432);             // 16 MB
    float* Y3    = (float*)(un + 50331648);             // 8 MB
    float* lw1T  = (float*)(un + 58720256);             // 2 MB
    float* mw1T  = (float*)(un + 60817408);             // 1 MB
    float* mw2T  = (float*)(un + 61865984);             // 128 KB
    float* hwT   = (float*)(un + 61997056);             // 25.6 KB
    float* Y1    = (float*)base;                        // aliases catD (dead after d2f)
    char* tail = base + 2u * 67108864u;
    int*    idxb  = (int*)tail;                         // 1.25 MB
    double* xD    = (double*)(tail + 1310720);          // 384 KB
    double* xxD   = (double*)(tail + 1703936);          // 128 KB
    double* wmodD = (double*)(tail + 1835008);          // 512 KB
    double* sumsD = (double*)(tail + 2359296);          // 8 KB
    double* ssbD  = (double*)(tail + 2367488);          // 8 KB
    float*  sumsF = (float*)(tail + 2375680);           // 8 KB
    float*  ssbF  = (float*)(tail + 2383872);           // 8 KB

    // ---- x -> fp64 ----
    f2d_kernel<<<(NROWS * 3 + 255) / 256, 256, 0, stream>>>(x, xD, (long)NROWS * 3);

    // ---- 4 EdgeConv layers (all fp64) ----
    const double* Fin[4] = {xD, catD + 0, catD + 64, catD + 128};
    const int   ldaL[4] = {3, 512, 512, 512};
    const int   CL[4]   = {3, 64, 64, 128};
    const int   OL[4]   = {64, 64, 128, 256};
    const int   coff[4] = {0, 64, 128, 256};

    for (int l = 0; l < 4; ++l) {
        const double* F = Fin[l];
        const int lda = ldaL[l], C = CL[l], O = OL[l];
        const int shiftO = (O == 64) ? 6 : (O == 128) ? 7 : 8;

        wmod_kernel_d<<<(O * C + 255) / 256, 256, 0, stream>>>(w[l], wmodD, O, C);
        xx_kernel_d<<<NROWS / 256, 256, 0, stream>>>(F, lda, C, xxD);

        for (int p = 0; p < 4; ++p) {           // 2 batches per dispatch
            const int b0 = p * 2;
            gemm64_dist<<<dim3(272, 2), 256, 0, stream>>>(F, lda, C, xxD, D, b0);
            topk2<<<dim3(NP / 4, 2), 256, 0, stream>>>(D, idxb, b0);
        }

        gemm64<<<dim3((2 * O) / 64, NROWS / 128), 256, 0, stream>>>(
            F, lda, wmodD, C, PQ, 2 * O, C);

        hipMemsetAsync(sumsD, 0, 2 * O * sizeof(double), stream);
        edge_gather<<<NROWS / 16, 256, 0, stream>>>(PQ, idxb, O, shiftO, sumsD,
                                                    catD + coff[l], 512);
        bn_finalize_d<<<(O + 255) / 256, 256, 0, stream>>>(sumsD, g[l], bb[l], ssbD, O,
                                                           1.0 / ((double)NROWS * KNBR));
        bn_apply<<<(NROWS * O) / 256, 256, 0, stream>>>(catD + coff[l], 512, ssbD,
                                                        O, shiftO, PQ, idxb);
    }

    // ---- cat fp64 -> fp32 (catD region becomes free -> Y1) ----
    d2f_kernel<<<((long)NROWS * 512 + 255) / 256, 256, 0, stream>>>(catD, cat32, (long)NROWS * 512);

    // ---- weight transposes ----
    transpose_kernel<<<(512 * 1024 + 255) / 256, 256, 0, stream>>>(lw1, lw1T, 512, 1024);
    transpose_kernel<<<(1024 * 256 + 255) / 256, 256, 0, stream>>>(mw1, mw1T, 1024, 256);
    transpose_kernel<<<(256 * 128 + 255) / 256, 256, 0, stream>>>(mw2, mw2T, 256, 128);
    transpose_kernel<<<(128 * 50 + 255) / 256, 256, 0, stream>>>(hw, hwT, 128, 50);

    // ---- MLP (fp32) ----
    {
        dim3 gg(1024 / 128, NROWS / 128);
        gemm_f32<<<gg, 256, 0, stream>>>(cat32, 512, lw1T, 512, Y1, 1024,
                                         NROWS, 1024, 512, 2, lb1, nullptr);
        hipMemsetAsync(sumsF, 0, 2 * 1024 * sizeof(float), stream);
        col_stats<<<dim3(1024 / 128, 64), 128, 0, stream>>>(Y1, 1024, sumsF);
        bn_finalize_f<<<4, 256, 0, stream>>>(sumsF, lg1, lbb1, ssbF, 1024, 1.f / NROWS);
    }
    {
        dim3 gg(256 / 128, NROWS / 128);
        gemm_f32<<<gg, 256, 0, stream>>>(Y1, 1024, mw1T, 1024, Y2, 256,
                                         NROWS, 256, 1024, 2, mb1, ssbF);
        hipMemsetAsync(sumsF, 0, 2 * 256 * sizeof(float), stream);
        col_stats<<<dim3(256 / 128, 64), 128, 0, stream>>>(Y2, 256, sumsF);
        bn_finalize_f<<<1, 256, 0, stream>>>(sumsF, mg1, mbb1, ssbF, 256, 1.f / NROWS);
    }
    {
        dim3 gg(1, NROWS / 128);
        gemm_f32<<<gg, 256, 0, stream>>>(Y2, 256, mw2T, 256, Y3, 128,
                                         NROWS, 128, 256, 2, mb2, ssbF);
        hipMemsetAsync(sumsF, 0, 2 * 128 * sizeof(float), stream);
        col_stats<<<dim3(1, 64), 128, 0, stream>>>(Y3, 128, sumsF);
        bn_finalize_f<<<1, 256, 0, stream>>>(sumsF, mg2, mbb2, ssbF, 128, 1.f / NROWS);
    }
    {
        dim3 gg(1, NROWS / 128);
        gemm_f32<<<gg, 256, 0, stream>>>(Y3, 128, hwT, 128, out, 50,
                                         NROWS, 50, 128, 3, hb, ssbF);
        log_softmax_kernel<<<NROWS / 4, 256, 0, stream>>>(out);
    }
}